// Round 2
// baseline (858.968 us; speedup 1.0000x reference)
//
#include <hip/hip_runtime.h>

// HNM discriminative loss, MI355X — R5.
// predict (4,32,512,1024) f32, target (4,512,1024) i32 -> scalar f32.
// R5 theory: R4 proved output path irrelevant (atomics->stores: dur identical
// 357.3us). Both passes run at ~750-840 GB/s effective with HBM 395 GB/s AND
// L3 ~360 GB/s both idle -> request-issue limited. Evidence: VGPR=28 proves
// R3's 8-outstanding-loads never materialized (needs >=32 VGPR); occupancy
// 31% (grid-limited, 2.5 blocks/CU). Fix both levers:
//   (a) 512-thread blocks, __launch_bounds__(512,4): 2 blocks/CU = 16 waves.
//   (b) channel-outer loop + explicit 4-slot ring prefetch + sched_barrier(0)
//       after each prefetch so the compiler cannot sink loads to the consumer
//       (the VGPR=28 failure). Guarantees 4 float4/wave in flight; each 8KB
//       channel chunk read as one burst.
// Discriminator: if durations hold at ~357/315 despite 3x request concurrency,
// the cap is allocation-level (page-walk rate ~750 GB/s) -> two-pass floor.

#define K_CLS 19
#define C_CH 32
#define HW_SHIFT 19            // H*W = 512*1024 = 2^19
#define HW_SIZE (1 << HW_SHIFT)
#define CHUNK 2048             // pixels per block (512 thr * 4 px)
#define EPSF 1e-12f
#define THEA_F 0.5f
#define TWO_DELTA 3.0f
#define MIN_PIX 20.0f

// ws float layout (identical footprint to R4, which passed)
#define NBLK 1024              // P / CHUNK
#define PART_STRIDE 632        // 627 used, padded
#define OFF_PART 0                                  // [blk][PART_STRIDE]: 608 sums + 19 counts
#define OFF_RED  (NBLK * PART_STRIDE)               // 627 reduced
#define OFF_VPART (OFF_RED + 640)                   // [blk][64]: 19 sq + 19 pos
#define WS_FLOATS (OFF_VPART + NBLK * 64)

__device__ __forceinline__ void atomAddF(float* p, float v) {
  unsafeAtomicAdd(p, v);       // LDS: ds_add_f32
}

// ---- Pass 1: per-class counts + feature sums -> private slot -------------
__global__ __launch_bounds__(512, 4) void k_accum(
    const float* __restrict__ pred, const int* __restrict__ tgt,
    float* __restrict__ ws)
{
  __shared__ float s_sums[C_CH][4][20];   // replica per quarter-wave
  __shared__ float s_cnt[4][20];
  {
    float* z = &s_sums[0][0][0];
    for (int i = threadIdx.x; i < C_CH * 4 * 20; i += 512) z[i] = 0.f;
    if (threadIdx.x < 80) (&s_cnt[0][0])[threadIdx.x] = 0.f;
  }

  const int t = threadIdx.x;
  const int rep = (t >> 4) & 3;
  const size_t P0 = (size_t)blockIdx.x * CHUNK;   // 2048 | 2^19: never crosses image
  const int n_idx = (int)(P0 >> HW_SHIFT);
  const int hw0 = (int)(P0 & (HW_SIZE - 1));

  const int4 t0 = *reinterpret_cast<const int4*>(tgt + P0 + t * 4);
  int  sc[4] = {t0.x, t0.y, t0.z, t0.w};
  bool vl[4];
#pragma unroll
  for (int i = 0; i < 4; ++i) { vl[i] = (unsigned)sc[i] < K_CLS; if (!vl[i]) sc[i] = 0; }

  __syncthreads();

#pragma unroll
  for (int i = 0; i < 4; ++i) if (vl[i]) atomAddF(&s_cnt[rep][sc[i]], 1.f);

  const float* base = pred + (((size_t)n_idx * C_CH) << HW_SHIFT) + hw0;

  // 4-slot ring: channel ch consumed 4 iterations after its load issues.
  float4 buf[4];
#pragma unroll
  for (int c = 0; c < 4; ++c)
    buf[c] = *reinterpret_cast<const float4*>(base + ((size_t)c << HW_SHIFT) + t * 4);
  __builtin_amdgcn_sched_barrier(0);

#pragma unroll
  for (int ch = 0; ch < C_CH; ++ch) {
    const int slot = ch & 3;
    const float4 v = buf[slot];
    if (ch + 4 < C_CH)
      buf[slot] = *reinterpret_cast<const float4*>(
          base + ((size_t)(ch + 4) << HW_SHIFT) + t * 4);
    __builtin_amdgcn_sched_barrier(0);   // pin: prefetch issues here, not at use
    const float x[4] = {v.x, v.y, v.z, v.w};
#pragma unroll
    for (int i = 0; i < 4; ++i) if (vl[i]) atomAddF(&s_sums[ch][rep][sc[i]], x[i]);
  }

  __syncthreads();
  float* part = ws + OFF_PART + (size_t)blockIdx.x * PART_STRIDE;
  for (int i = t; i < C_CH * K_CLS; i += 512) {
    const int ch = i / K_CLS, k = i - ch * K_CLS;
    part[i] = s_sums[ch][0][k] + s_sums[ch][1][k] + s_sums[ch][2][k] + s_sums[ch][3][k];
  }
  if (t < K_CLS)
    part[C_CH * K_CLS + t] = s_cnt[0][t] + s_cnt[1][t] + s_cnt[2][t] + s_cnt[3][t];
}

// ---- Reduce 1024 partial slots -> 627 totals ------------------------------
__global__ __launch_bounds__(256) void k_reduce(float* __restrict__ ws, int nb)
{
  const int o = blockIdx.x;            // 0..626
  const int t = threadIdx.x;
  float a = 0.f;
  for (int b = t; b < nb; b += 256)
    a += ws[OFF_PART + (size_t)b * PART_STRIDE + o];
#pragma unroll
  for (int d = 32; d > 0; d >>= 1) a += __shfl_down(a, d, 64);
  __shared__ float s[4];
  if ((t & 63) == 0) s[t >> 6] = a;
  __syncthreads();
  if (t == 0) ws[OFF_RED + o] = s[0] + s[1] + s[2] + s[3];
}

// ---- Pass 2: per-pixel residuals (d^2 in registers) -> sq/pos slot --------
__global__ __launch_bounds__(512, 4) void k_var(
    const float* __restrict__ pred, const int* __restrict__ tgt,
    float* __restrict__ ws)
{
  __shared__ float s_ctr[C_CH][K_CLS];
  __shared__ float s_sq[K_CLS];
  __shared__ float s_pos[K_CLS];
  for (int i = threadIdx.x; i < C_CH * K_CLS; i += 512) {
    const int k = i % K_CLS;
    (&s_ctr[0][0])[i] = ws[OFF_RED + i] / fmaxf(ws[OFF_RED + C_CH * K_CLS + k], 1.f);
  }
  if (threadIdx.x < K_CLS) { s_sq[threadIdx.x] = 0.f; s_pos[threadIdx.x] = 0.f; }

  const int t = threadIdx.x;
  const size_t P0 = (size_t)blockIdx.x * CHUNK;
  const int n_idx = (int)(P0 >> HW_SHIFT);
  const int hw0 = (int)(P0 & (HW_SIZE - 1));

  const int4 t0 = *reinterpret_cast<const int4*>(tgt + P0 + t * 4);
  int  sc[4] = {t0.x, t0.y, t0.z, t0.w};
  bool vl[4];
#pragma unroll
  for (int i = 0; i < 4; ++i) { vl[i] = (unsigned)sc[i] < K_CLS; if (!vl[i]) sc[i] = 0; }

  __syncthreads();

  float d2[4] = {0.f, 0.f, 0.f, 0.f};
  const float* base = pred + (((size_t)n_idx * C_CH) << HW_SHIFT) + hw0;

  float4 buf[4];
#pragma unroll
  for (int c = 0; c < 4; ++c)
    buf[c] = *reinterpret_cast<const float4*>(base + ((size_t)c << HW_SHIFT) + t * 4);
  __builtin_amdgcn_sched_barrier(0);

#pragma unroll
  for (int ch = 0; ch < C_CH; ++ch) {
    const int slot = ch & 3;
    const float4 v = buf[slot];
    if (ch + 4 < C_CH)
      buf[slot] = *reinterpret_cast<const float4*>(
          base + ((size_t)(ch + 4) << HW_SHIFT) + t * 4);
    __builtin_amdgcn_sched_barrier(0);
    const float x[4] = {v.x, v.y, v.z, v.w};
#pragma unroll
    for (int i = 0; i < 4; ++i) {
      const float c = s_ctr[ch][sc[i]];   // same-addr broadcast / 19 banks: conflict-free
      const float d = c - x[i];
      d2[i] = fmaf(d, d, d2[i]);
    }
  }

#pragma unroll
  for (int i = 0; i < 4; ++i) {
    if (vl[i]) {
      const float r = sqrtf(d2[i] + EPSF) - THEA_F;
      if (r > 0.f) { atomAddF(&s_sq[sc[i]], r * r); atomAddF(&s_pos[sc[i]], 1.f); }
    }
  }

  __syncthreads();
  if (t < K_CLS) {
    float* vp = ws + OFF_VPART + (size_t)blockIdx.x * 64;
    vp[t]         = s_sq[t];
    vp[K_CLS + t] = s_pos[t];
  }
}

// ---- Finalize: reduce vparts, then loss_var + loss_dis + 0.001*loss_reg ---
__global__ __launch_bounds__(1024) void k_final(
    float* __restrict__ ws, float* __restrict__ out, int nb)
{
  __shared__ float s_ctr[C_CH * K_CLS];
  __shared__ float s_valid[K_CLS];
  __shared__ float s_sq[K_CLS];
  __shared__ float s_pos[K_CLS];
  __shared__ float s_red[3];
  __shared__ float s_ncls;
  const int t = threadIdx.x;
  if (t < 3) s_red[t] = 0.f;
  if (t < K_CLS) { s_sq[t] = 0.f; s_pos[t] = 0.f; }
  if (t < K_CLS) s_valid[t] = (ws[OFF_RED + C_CH * K_CLS + t] > MIN_PIX) ? 1.f : 0.f;
  for (int i = t; i < C_CH * K_CLS; i += 1024) {
    const int k = i % K_CLS;
    s_ctr[i] = ws[OFF_RED + i] / fmaxf(ws[OFF_RED + C_CH * K_CLS + k], 1.f);
  }
  __syncthreads();

  // reduce per-block sq/pos slots: 16 slices x 64 slots (38 live)
  {
    const int o = t & 63, slice = t >> 6;
    if (o < 2 * K_CLS) {
      float a = 0.f;
      for (int b = slice; b < nb; b += 16)
        a += ws[OFF_VPART + (size_t)b * 64 + o];
      atomAddF(o < K_CLS ? &s_sq[o] : &s_pos[o - K_CLS], a);
    }
  }
  __syncthreads();

  if (t == 0) {
    float n = 0.f;
    for (int k = 0; k < K_CLS; ++k) n += s_valid[k];
    s_ncls = fmaxf(n, 1.f);
  }
  if (t < K_CLS && s_valid[t] > 0.f) {
    atomAddF(&s_red[0], s_sq[t] / fmaxf(s_pos[t], 1.f));
    float nn = 0.f;
#pragma unroll
    for (int ch = 0; ch < C_CH; ++ch) {
      const float cv = s_ctr[ch * K_CLS + t];
      nn = fmaf(cv, cv, nn);
    }
    atomAddF(&s_red[2], sqrtf(nn + EPSF));
  }
  if (t < K_CLS * K_CLS) {
    const int a = t / K_CLS, b = t - (t / K_CLS) * K_CLS;
    if (a != b && s_valid[a] > 0.f && s_valid[b] > 0.f) {
      float dd = 0.f;
#pragma unroll
      for (int ch = 0; ch < C_CH; ++ch) {
        const float df = s_ctr[ch * K_CLS + a] - s_ctr[ch * K_CLS + b];
        dd = fmaf(df, df, dd);
      }
      const float dist = sqrtf(dd + EPSF);
      const float d = fmaxf(TWO_DELTA - dist, 0.f);
      if (d > 0.f) atomAddF(&s_red[1], d * d);
    }
  }
  __syncthreads();
  if (t == 0) {
    const float n = s_ncls;
    out[0] = s_red[0] / n
           + s_red[1] / fmaxf(n * (n - 1.f), 1.f)
           + 0.001f * s_red[2] / n;
  }
}

extern "C" void kernel_launch(void* const* d_in, const int* in_sizes, int n_in,
                              void* d_out, int out_size, void* d_ws, size_t ws_size,
                              hipStream_t stream) {
  const float* pred = (const float*)d_in[0];
  const int*   tgt  = (const int*)d_in[1];
  float* ws  = (float*)d_ws;
  float* out = (float*)d_out;
  const int P = in_sizes[1];            // n*h*w = 2097152
  const int nBlocks = P / CHUNK;        // 1024

  k_accum <<<nBlocks, 512, 0, stream>>>(pred, tgt, ws);
  k_reduce<<<C_CH * K_CLS + K_CLS, 256, 0, stream>>>(ws, nBlocks);
  k_var   <<<nBlocks, 512, 0, stream>>>(pred, tgt, ws);
  k_final <<<1, 1024, 0, stream>>>(ws, out, nBlocks);
}

// Round 3
// 562.515 us; speedup vs baseline: 1.5270x; 1.5270x over previous
//
#include <hip/hip_runtime.h>

// HNM discriminative loss, MI355X — R6.
// predict (4,32,512,1024) f32, target (4,512,1024) i32 -> scalar f32.
// R6: R5 killed the request-concurrency theory (4-deep ring + 60% occupancy,
// k_accum still 355.1 vs 357.3 us). Two survivors, attacked per-kernel:
//  (1) LDS-atomic drain: 852K cy/CU / 4.2K wave-atomics = 202 cy each — fits
//      k_accum exactly. Fix: k_accum v3 = channel-slab blocks (sums are
//      per-(ch,k) separable) + mask-FMA into acc[19] registers. ZERO atomics,
//      ZERO random LDS, and each block reads 256KB fully contiguous.
//  (2) per-CU read-stream cap (~3.4 B/cy) on 2MB-strided multi-streams: fix
//      for the non-separable k_var = global_load_lds double-buffered staging
//      (different path than VGPR loads), counted vmcnt(9), wave-private (no
//      barriers). R5's sched_barrier pinning reverted (it cost k_var +160us).

#define K_CLS 19
#define C_CH 32
#define HW_SHIFT 19            // H*W = 512*1024 = 2^19
#define HW_SIZE (1 << HW_SHIFT)
#define EPSF 1e-12f
#define THEA_F 0.5f
#define TWO_DELTA 3.0f
#define MIN_PIX 20.0f

// ---- ws float layout (no atomics; every cell written before read) --------
// k_accum v3: 1024 blocks = 128 planes x 8 slabs; partial sums [ch][32 slots][20]
#define OFF_PSUM 0                       // 32*32*20 = 20480
#define OFF_PCNT 20480                   // 32 slots * 20 = 640
#define OFF_RED  21120                   // 608 sums (ch*19+k) + counts at +608 (pad to 640)
#define OFF_VPART 21760                  // [1024 blk][64]: 19 sq + 19 pos
#define WS_FLOATS (OFF_VPART + 1024 * 64)

typedef const unsigned int __attribute__((address_space(1)))* GP;
typedef unsigned int __attribute__((address_space(3)))* LP;

__device__ __forceinline__ void atomAddF(float* p, float v) {
  unsafeAtomicAdd(p, v);       // LDS ds_add_f32 (cold paths only)
}

// ---- Pass 1 v3: one block = one (plane, slab); mask-FMA binning ----------
// plane = n*32+ch (128), slab = 64K px (8/plane). Reads 256KB pred + 256KB
// cls, both contiguous. acc[19] in registers; flush = 6-level shfl once.
__global__ __launch_bounds__(256) void k_accum(
    const float* __restrict__ pred, const int* __restrict__ tgt,
    float* __restrict__ ws)
{
  const int t = threadIdx.x;
  const int plane = blockIdx.x >> 3;       // 0..127
  const int slab  = blockIdx.x & 7;        // 0..7
  const int n_idx = plane >> 5;
  const int ch    = plane & 31;

  const float* pbase = pred + (((size_t)plane) << HW_SHIFT) + ((size_t)slab << 16);
  const int*   tbase = tgt  + (((size_t)n_idx) << HW_SHIFT) + ((size_t)slab << 16);

  float acc[K_CLS];
#pragma unroll
  for (int k = 0; k < K_CLS; ++k) acc[k] = 0.f;

  // software-pipelined 2-deep: load batch it+1 while binning batch it
  float4 vA = *reinterpret_cast<const float4*>(pbase + t * 4);
  int4   cA = *reinterpret_cast<const int4*>(tbase + t * 4);
#pragma unroll 1
  for (int it = 0; it < 64; ++it) {
    float4 vB; int4 cB;
    if (it + 1 < 64) {
      vB = *reinterpret_cast<const float4*>(pbase + (it + 1) * 1024 + t * 4);
      cB = *reinterpret_cast<const int4*>(tbase + (it + 1) * 1024 + t * 4);
    }
    const float x[4] = {vA.x, vA.y, vA.z, vA.w};
    const int   s[4] = {cA.x, cA.y, cA.z, cA.w};
#pragma unroll
    for (int k = 0; k < K_CLS; ++k) {
#pragma unroll
      for (int i = 0; i < 4; ++i)
        acc[k] += (s[i] == k) ? x[i] : 0.f;   // cls=255 matches nothing
    }
    vA = vB; cA = cB;
  }

  // wave-reduce 19 accumulators, then block-combine via tiny LDS
  __shared__ float s_w[4][20];
  const int w = t >> 6;
#pragma unroll
  for (int k = 0; k < K_CLS; ++k) {
    float s = acc[k];
#pragma unroll
    for (int m = 1; m < 64; m <<= 1) s += __shfl_xor(s, m, 64);
    acc[k] = s;
  }
  if ((t & 63) < K_CLS) {
    // lane k of each wave holds the wave total for every k; write own k
    const int k = t & 63;
    s_w[w][k] = acc[k];
  }
  __syncthreads();
  if (t < K_CLS) {
    const int slot = n_idx * 8 + slab;
    ws[OFF_PSUM + ch * 640 + slot * 20 + t] =
        s_w[0][t] + s_w[1][t] + s_w[2][t] + s_w[3][t];
  }

  // counts: only ch==0 blocks (each pixel counted once)
  if (ch == 0) {
    float cnt[K_CLS];
#pragma unroll
    for (int k = 0; k < K_CLS; ++k) cnt[k] = 0.f;
#pragma unroll 1
    for (int it = 0; it < 64; ++it) {
      const int4 c4 = *reinterpret_cast<const int4*>(tbase + it * 1024 + t * 4);
      const int s[4] = {c4.x, c4.y, c4.z, c4.w};
#pragma unroll
      for (int k = 0; k < K_CLS; ++k) {
#pragma unroll
        for (int i = 0; i < 4; ++i) cnt[k] += (s[i] == k) ? 1.f : 0.f;
      }
    }
    __shared__ float s_c[4][20];
#pragma unroll
    for (int k = 0; k < K_CLS; ++k) {
      float s = cnt[k];
#pragma unroll
      for (int m = 1; m < 64; m <<= 1) s += __shfl_xor(s, m, 64);
      cnt[k] = s;
    }
    if ((t & 63) < K_CLS) s_c[w][t & 63] = cnt[t & 63];
    __syncthreads();
    if (t < K_CLS) {
      const int slot = n_idx * 8 + slab;
      ws[OFF_PCNT + slot * 20 + t] = s_c[0][t] + s_c[1][t] + s_c[2][t] + s_c[3][t];
    }
  }
}

// ---- Reduce 32 slots -> 627 totals (single small block) -------------------
__global__ __launch_bounds__(256) void k_reduce(float* __restrict__ ws)
{
  const int t = threadIdx.x;
  for (int o = t; o < C_CH * K_CLS; o += 256) {
    const int ch = o / K_CLS, k = o - ch * K_CLS;
    float a = 0.f;
#pragma unroll 4
    for (int s = 0; s < 32; ++s) a += ws[OFF_PSUM + ch * 640 + s * 20 + k];
    ws[OFF_RED + o] = a;
  }
  if (t < K_CLS) {
    float a = 0.f;
#pragma unroll 4
    for (int s = 0; s < 32; ++s) a += ws[OFF_PCNT + s * 20 + t];
    ws[OFF_RED + C_CH * K_CLS + t] = a;
  }
}

// ---- Pass 2 v3: global_load_lds staged, px-per-lane windows ---------------
// Block = 2048 px, 4 waves x 512 px; wave window = 64 px (1 px/lane), 8
// windows, double-buffered wave-private LDS staging. vmcnt counted (9), no
// barriers in the pipeline (wave-private buffers).
__global__ __launch_bounds__(256) void k_var(
    const float* __restrict__ pred, const int* __restrict__ tgt,
    float* __restrict__ ws)
{
  __shared__ float s_buf[4][2][C_CH][64];   // 64 KB
  __shared__ int   s_cls[4][2][256];        // 8 KB (only first 64 ints used)
  __shared__ float s_ctr[C_CH][K_CLS];
  __shared__ float s_sq[K_CLS];
  __shared__ float s_pos[K_CLS];

  const int t = threadIdx.x;
  const int w = t >> 6;
  const int lane = t & 63;

  for (int i = t; i < C_CH * K_CLS; i += 256) {
    const int k = i % K_CLS;
    (&s_ctr[0][0])[i] = ws[OFF_RED + i] / fmaxf(ws[OFF_RED + C_CH * K_CLS + k], 1.f);
  }
  if (t < K_CLS) { s_sq[t] = 0.f; s_pos[t] = 0.f; }
  __syncthreads();

  const size_t P0 = (size_t)blockIdx.x * 2048;
  const int n_idx = (int)(P0 >> HW_SHIFT);
  const int hw0 = (int)(P0 & (HW_SIZE - 1));
  const int qch = lane >> 4;                 // 0..3: sub-channel within a load
  const int qpx = (lane & 15) * 4;           // 0..60: px offset within row

  // stage window j into half h: 8 pred loads (4 ch each) + 1 cls load
#define STAGE(h, j)                                                           \
  {                                                                           \
    const int pw = hw0 + w * 512 + (j) * 64;                                  \
    _Pragma("unroll")                                                         \
    for (int q = 0; q < 8; ++q) {                                             \
      const int c = q * 4 + qch;                                              \
      const float* gp = pred + (((size_t)(n_idx * C_CH + c)) << HW_SHIFT)     \
                        + pw + qpx;                                           \
      __builtin_amdgcn_global_load_lds((GP)gp, (LP)&s_buf[w][h][0][0] + q * 256, \
                                       16, 0, 0);                             \
    }                                                                         \
    const int* gt = tgt + (((size_t)n_idx) << HW_SHIFT) + pw + qpx;           \
    __builtin_amdgcn_global_load_lds((GP)gt, (LP)&s_cls[w][h][0], 16, 0, 0);  \
  }

  float res8[8];
  int   cls8[8];

  STAGE(0, 0)
#pragma unroll 1
  for (int j = 0; j < 8; ++j) {
    const int h = j & 1;
    if (j < 7) {
      STAGE(h ^ 1, j + 1)
      asm volatile("s_waitcnt vmcnt(9)" ::: "memory");
    } else {
      asm volatile("s_waitcnt vmcnt(0)" ::: "memory");
    }
    __builtin_amdgcn_sched_barrier(0);

    const int ci = s_cls[w][h][lane];
    const bool vld = (unsigned)ci < K_CLS;
    const int sc = vld ? ci : 0;
    float d2 = 0.f;
#pragma unroll
    for (int c = 0; c < C_CH; ++c) {
      const float x = s_buf[w][h][c][lane];
      const float d = s_ctr[c][sc] - x;
      d2 = fmaf(d, d, d2);
    }
    res8[j] = d2;
    cls8[j] = vld ? ci : -1;
  }

#pragma unroll
  for (int j = 0; j < 8; ++j) {
    if (cls8[j] >= 0) {
      const float r = sqrtf(res8[j] + EPSF) - THEA_F;
      if (r > 0.f) { atomAddF(&s_sq[cls8[j]], r * r); atomAddF(&s_pos[cls8[j]], 1.f); }
    }
  }

  __syncthreads();
  if (t < K_CLS) {
    float* vp = ws + OFF_VPART + (size_t)blockIdx.x * 64;
    vp[t]         = s_sq[t];
    vp[K_CLS + t] = s_pos[t];
  }
#undef STAGE
}

// ---- Finalize: reduce vparts, then loss_var + loss_dis + 0.001*loss_reg ---
__global__ __launch_bounds__(1024) void k_final(
    float* __restrict__ ws, float* __restrict__ out, int nb)
{
  __shared__ float s_ctr[C_CH * K_CLS];
  __shared__ float s_valid[K_CLS];
  __shared__ float s_sq[K_CLS];
  __shared__ float s_pos[K_CLS];
  __shared__ float s_red[3];
  __shared__ float s_ncls;
  const int t = threadIdx.x;
  if (t < 3) s_red[t] = 0.f;
  if (t < K_CLS) { s_sq[t] = 0.f; s_pos[t] = 0.f; }
  if (t < K_CLS) s_valid[t] = (ws[OFF_RED + C_CH * K_CLS + t] > MIN_PIX) ? 1.f : 0.f;
  for (int i = t; i < C_CH * K_CLS; i += 1024) {
    const int k = i % K_CLS;
    s_ctr[i] = ws[OFF_RED + i] / fmaxf(ws[OFF_RED + C_CH * K_CLS + k], 1.f);
  }
  __syncthreads();

  {
    const int o = t & 63, slice = t >> 6;
    if (o < 2 * K_CLS) {
      float a = 0.f;
      for (int b = slice; b < nb; b += 16)
        a += ws[OFF_VPART + (size_t)b * 64 + o];
      atomAddF(o < K_CLS ? &s_sq[o] : &s_pos[o - K_CLS], a);
    }
  }
  __syncthreads();

  if (t == 0) {
    float n = 0.f;
    for (int k = 0; k < K_CLS; ++k) n += s_valid[k];
    s_ncls = fmaxf(n, 1.f);
  }
  if (t < K_CLS && s_valid[t] > 0.f) {
    atomAddF(&s_red[0], s_sq[t] / fmaxf(s_pos[t], 1.f));
    float nn = 0.f;
#pragma unroll
    for (int ch = 0; ch < C_CH; ++ch) {
      const float cv = s_ctr[ch * K_CLS + t];
      nn = fmaf(cv, cv, nn);
    }
    atomAddF(&s_red[2], sqrtf(nn + EPSF));
  }
  if (t < K_CLS * K_CLS) {
    const int a = t / K_CLS, b = t - (t / K_CLS) * K_CLS;
    if (a != b && s_valid[a] > 0.f && s_valid[b] > 0.f) {
      float dd = 0.f;
#pragma unroll
      for (int ch = 0; ch < C_CH; ++ch) {
        const float df = s_ctr[ch * K_CLS + a] - s_ctr[ch * K_CLS + b];
        dd = fmaf(df, df, dd);
      }
      const float dist = sqrtf(dd + EPSF);
      const float d = fmaxf(TWO_DELTA - dist, 0.f);
      if (d > 0.f) atomAddF(&s_red[1], d * d);
    }
  }
  __syncthreads();
  if (t == 0) {
    const float n = s_ncls;
    out[0] = s_red[0] / n
           + s_red[1] / fmaxf(n * (n - 1.f), 1.f)
           + 0.001f * s_red[2] / n;
  }
}

extern "C" void kernel_launch(void* const* d_in, const int* in_sizes, int n_in,
                              void* d_out, int out_size, void* d_ws, size_t ws_size,
                              hipStream_t stream) {
  const float* pred = (const float*)d_in[0];
  const int*   tgt  = (const int*)d_in[1];
  float* ws  = (float*)d_ws;
  float* out = (float*)d_out;
  const int P = in_sizes[1];            // n*h*w = 2097152
  const int nBlocksVar = P / 2048;      // 1024

  k_accum <<<1024, 256, 0, stream>>>(pred, tgt, ws);          // 128 planes x 8 slabs
  k_reduce<<<1, 256, 0, stream>>>(ws);
  k_var   <<<nBlocksVar, 256, 0, stream>>>(pred, tgt, ws);
  k_final <<<1, 1024, 0, stream>>>(ws, out, nBlocksVar);
}